// Round 1
// baseline (810.603 us; speedup 1.0000x reference)
//
#include <hip/hip_runtime.h>
#include <hip/hip_fp16.h>

typedef _Float16 f16;
typedef f16 f16x8 __attribute__((ext_vector_type(8)));
typedef f16 f16x4 __attribute__((ext_vector_type(4)));
typedef float f32x4 __attribute__((ext_vector_type(4)));

constexpr int Bb = 8, Cc = 1024, Tt = 2048, Ci = 512;
constexpr float BN_EPS = 1e-5f;

// ---------------- fp32 -> fp16 convert ----------------
__global__ __launch_bounds__(256)
void cvt_kernel(const float* __restrict__ src, f16* __restrict__ dst, int n4) {
  int i = blockIdx.x * blockDim.x + threadIdx.x;
  if (i < n4) {
    float4 v = *((const float4*)src + i);
    f16x4 h;
    h[0] = (f16)v.x; h[1] = (f16)v.y; h[2] = (f16)v.z; h[3] = (f16)v.w;
    *((f16x4*)dst + i) = h;
  }
}

// ---------------- generic f16 MFMA GEMM ----------------
// C[m,n] = sum_k A[m,k] * B[k,n]  (+ bias[m])
// A_KM: A stored [K, M] (row length lda = M-dim stride), else [M, K] (lda = K-dim stride)
// B always [K, N] row-major (ldb).
// DO_BN: accumulate per-row sum / sumsq (over all n, all batches) into bn_sum/bn_sumsq.
template<bool A_KM, bool DO_BN>
__global__ __launch_bounds__(256)
void gemm16(const f16* __restrict__ A, const f16* __restrict__ Bm,
            f16* __restrict__ Cm, const float* __restrict__ bias,
            float* __restrict__ bn_sum, float* __restrict__ bn_sumsq,
            int M, int N, int K, int lda, int ldb, int ldc,
            long sA, long sB, long sC)
{
  constexpr int BM = 64, BN = 64, BK = 32, PAD = 16; // stride 48 halves = 96B (16B-aligned)
  __shared__ f16 la[BM][BK + PAD];
  __shared__ f16 lb[BN][BK + PAD];
  __shared__ float lsum[BM], lsq[BM];

  const int tid  = threadIdx.x;
  const int lane = tid & 63;
  const int wv   = tid >> 6;
  const int wm   = (wv >> 1) * 32;
  const int wn   = (wv & 1) * 32;
  const int bm0  = blockIdx.y * BM;
  const int bn0  = blockIdx.x * BN;
  const int bz   = blockIdx.z;

  A  += (long)bz * sA;
  Bm += (long)bz * sB;
  Cm += (long)bz * sC;

  if (DO_BN && tid < BM) { lsum[tid] = 0.f; lsq[tid] = 0.f; }

  f32x4 acc[2][2] = {};

  const int row16 = lane & 15;
  const int kb    = (lane >> 4) * 8;

  for (int k0 = 0; k0 < K; k0 += BK) {
    __syncthreads();
    // ---- stage A tile: la[m][k] ----
    if (!A_KM) {
      int m  = tid >> 2;
      int kq = (tid & 3) * 8;
      f16x8 v = *(const f16x8*)(A + (long)(bm0 + m) * lda + k0 + kq);
      *(f16x8*)&la[m][kq] = v;
    } else {
      int k  = tid >> 3;
      int mq = (tid & 7) * 8;
      f16x8 v = *(const f16x8*)(A + (long)(k0 + k) * lda + bm0 + mq);
      #pragma unroll
      for (int j = 0; j < 8; j++) la[mq + j][k] = v[j];
    }
    // ---- stage B tile transposed: lb[n][k] ----
    {
      int k  = tid >> 3;
      int nq = (tid & 7) * 8;
      f16x8 v = *(const f16x8*)(Bm + (long)(k0 + k) * ldb + bn0 + nq);
      #pragma unroll
      for (int j = 0; j < 8; j++) lb[nq + j][k] = v[j];
    }
    __syncthreads();

    f16x8 af[2], bf[2];
    #pragma unroll
    for (int i = 0; i < 2; i++) {
      af[i] = *(const f16x8*)&la[wm + i * 16 + row16][kb];
      bf[i] = *(const f16x8*)&lb[wn + i * 16 + row16][kb];
    }
    #pragma unroll
    for (int i = 0; i < 2; i++)
      #pragma unroll
      for (int j = 0; j < 2; j++)
        acc[i][j] = __builtin_amdgcn_mfma_f32_16x16x32_f16(af[i], bf[j], acc[i][j], 0, 0, 0);
  }

  // ---- epilogue: bias, store f16, optional BN partial sums ----
  #pragma unroll
  for (int i = 0; i < 2; i++) {
    #pragma unroll
    for (int r = 0; r < 4; r++) {
      int rl   = wm + i * 16 + ((lane >> 4) << 2) + r;
      int grow = bm0 + rl;
      float bv = bias ? bias[grow] : 0.0f;
      float s1 = 0.f, s2 = 0.f;
      #pragma unroll
      for (int j = 0; j < 2; j++) {
        float v = acc[i][j][r] + bv;
        Cm[(long)grow * ldc + bn0 + wn + j * 16 + (lane & 15)] = (f16)v;
        if (DO_BN) { s1 += v; s2 += v * v; }
      }
      if (DO_BN) {
        #pragma unroll
        for (int off = 1; off < 16; off <<= 1) {
          s1 += __shfl_xor(s1, off);
          s2 += __shfl_xor(s2, off);
        }
        if ((lane & 15) == 0) { atomicAdd(&lsum[rl], s1); atomicAdd(&lsq[rl], s2); }
      }
    }
  }
  if (DO_BN) {
    __syncthreads();
    if (tid < BM) {
      atomicAdd(&bn_sum[bm0 + tid], lsum[tid]);
      atomicAdd(&bn_sumsq[bm0 + tid], lsq[tid]);
    }
  }
}

// ---------------- row softmax (in-place, rows of length Tt) ----------------
__global__ __launch_bounds__(256)
void softmax_kernel(f16* __restrict__ S) {
  __shared__ float red[8];
  const int tid = threadIdx.x;
  f16* p = S + (long)blockIdx.x * Tt;
  f16x8 v = *((const f16x8*)p + tid);
  float f[8];
  float mx = -3e38f;
  #pragma unroll
  for (int j = 0; j < 8; j++) { f[j] = (float)v[j]; mx = fmaxf(mx, f[j]); }
  #pragma unroll
  for (int off = 1; off < 64; off <<= 1) mx = fmaxf(mx, __shfl_xor(mx, off));
  const int w = tid >> 6;
  if ((tid & 63) == 0) red[w] = mx;
  __syncthreads();
  mx = fmaxf(fmaxf(red[0], red[1]), fmaxf(red[2], red[3]));
  float sum = 0.f;
  #pragma unroll
  for (int j = 0; j < 8; j++) { f[j] = __expf(f[j] - mx); sum += f[j]; }
  #pragma unroll
  for (int off = 1; off < 64; off <<= 1) sum += __shfl_xor(sum, off);
  __syncthreads();
  if ((tid & 63) == 0) red[4 + w] = sum;
  __syncthreads();
  sum = (red[4] + red[5]) + (red[6] + red[7]);
  float inv = 1.0f / sum;
  f16x8 o;
  #pragma unroll
  for (int j = 0; j < 8; j++) o[j] = (f16)(f[j] * inv);
  *((f16x8*)p + tid) = o;
}

// ---------------- finalize: BN + residual ----------------
__global__ __launch_bounds__(256)
void final_kernel(const f16* __restrict__ wy, const float* __restrict__ x,
                  const float* __restrict__ gamma, const float* __restrict__ beta,
                  const float* __restrict__ bsum, const float* __restrict__ bsq,
                  float* __restrict__ out)
{
  long i = ((long)blockIdx.x * blockDim.x + threadIdx.x) * 4;
  int c = (int)((i >> 11) & (Cc - 1)); // T = 2048 = 2^11
  const float cnt = (float)Bb * (float)Tt;
  float mean = bsum[c] / cnt;
  float var  = bsq[c] / cnt - mean * mean;
  float sc = rsqrtf(var + BN_EPS) * gamma[c];
  float sh = beta[c] - mean * sc;
  f16x4 w = *(const f16x4*)(wy + i);
  float4 xv = *(const float4*)(x + i);
  float4 o;
  o.x = (float)w[0] * sc + sh + xv.x;
  o.y = (float)w[1] * sc + sh + xv.y;
  o.z = (float)w[2] * sc + sh + xv.z;
  o.w = (float)w[3] * sc + sh + xv.w;
  *(float4*)(out + i) = o;
}

// ---------------- host launch ----------------
extern "C" void kernel_launch(void* const* d_in, const int* in_sizes, int n_in,
                              void* d_out, int out_size, void* d_ws, size_t ws_size,
                              hipStream_t stream) {
  const float* x    = (const float*)d_in[0];
  const float* Wq_w = (const float*)d_in[1];
  const float* Wq_b = (const float*)d_in[2];
  const float* Wk_w = (const float*)d_in[3];
  const float* Wk_b = (const float*)d_in[4];
  const float* Wv_w = (const float*)d_in[5];
  const float* Wv_b = (const float*)d_in[6];
  const float* Wo_w = (const float*)d_in[7];
  const float* Wo_b = (const float*)d_in[8];
  const float* gamma = (const float*)d_in[9];
  const float* beta  = (const float*)d_in[10];
  float* out = (float*)d_out;

  constexpr size_t SZ_XH = (size_t)Bb * Cc * Tt;   // halves
  constexpr size_t SZ_W  = (size_t)Ci * Cc;
  constexpr size_t SZ_QT = (size_t)Bb * Ci * Tt;
  constexpr size_t SZ_ST = (size_t)Bb * Tt * Tt;
  constexpr size_t SZ_WY = (size_t)Bb * Cc * Tt;

  f16* xh  = (f16*)d_ws;
  f16* wqh = xh + SZ_XH;
  f16* wkh = wqh + SZ_W;
  f16* wvh = wkh + SZ_W;
  f16* woh = wvh + SZ_W;
  f16* Qt  = woh + SZ_W;
  f16* Kt  = Qt + SZ_QT;
  f16* Vt  = Kt + SZ_QT;
  f16* St  = Vt + SZ_QT;
  f16* Y   = St + SZ_ST;
  f16* wyh = Y + SZ_QT;
  float* bsum = (float*)(wyh + SZ_WY);
  float* bsq  = bsum + Cc;

  hipMemsetAsync(bsum, 0, 2 * Cc * sizeof(float), stream);

  // converts
  cvt_kernel<<<(int)(SZ_XH / 4 + 255) / 256, 256, 0, stream>>>(x, xh, (int)(SZ_XH / 4));
  cvt_kernel<<<(int)(SZ_W / 4 + 255) / 256, 256, 0, stream>>>(Wq_w, wqh, (int)(SZ_W / 4));
  cvt_kernel<<<(int)(SZ_W / 4 + 255) / 256, 256, 0, stream>>>(Wk_w, wkh, (int)(SZ_W / 4));
  cvt_kernel<<<(int)(SZ_W / 4 + 255) / 256, 256, 0, stream>>>(Wv_w, wvh, (int)(SZ_W / 4));
  cvt_kernel<<<(int)(SZ_W / 4 + 255) / 256, 256, 0, stream>>>(Wo_w, woh, (int)(SZ_W / 4));

  // projections: Qt/Kt/Vt[b][o][t] = sum_c W[o,c] xh[b,c,t] + b[o]
  gemm16<false, false><<<dim3(Tt / 64, Ci / 64, Bb), 256, 0, stream>>>(
      wqh, xh, Qt, Wq_b, nullptr, nullptr,
      Ci, Tt, Cc, Cc, Tt, Tt, 0, (long)Cc * Tt, (long)Ci * Tt);
  gemm16<false, false><<<dim3(Tt / 64, Ci / 64, Bb), 256, 0, stream>>>(
      wkh, xh, Kt, Wk_b, nullptr, nullptr,
      Ci, Tt, Cc, Cc, Tt, Tt, 0, (long)Cc * Tt, (long)Ci * Tt);
  gemm16<false, false><<<dim3(Tt / 64, Ci / 64, Bb), 256, 0, stream>>>(
      wvh, xh, Vt, Wv_b, nullptr, nullptr,
      Ci, Tt, Cc, Cc, Tt, Tt, 0, (long)Cc * Tt, (long)Ci * Tt);

  // St[b][kt][q] = sum_c Kt[b][c][kt] * Qt[b][c][q]   (A = Kt in [K,M] layout)
  gemm16<true, false><<<dim3(Tt / 64, Tt / 64, Bb), 256, 0, stream>>>(
      Kt, Qt, St, nullptr, nullptr, nullptr,
      Tt, Tt, Ci, Tt, Tt, Tt, (long)Ci * Tt, (long)Ci * Tt, (long)Tt * Tt);

  // softmax over q (contiguous rows), in place
  softmax_kernel<<<Bb * Tt, 256, 0, stream>>>(St);

  // Y[b][c][q] = sum_k Vt[b][c][k] * Sm[b][k][q]
  gemm16<false, false><<<dim3(Tt / 64, Ci / 64, Bb), 256, 0, stream>>>(
      Vt, St, Y, nullptr, nullptr, nullptr,
      Ci, Tt, Tt, Tt, Tt, Tt, (long)Ci * Tt, (long)Tt * Tt, (long)Ci * Tt);

  // wy[b][o][t] = sum_c Wo[o,c] Y[b][c][t] + Wo_b[o]   (+ BN stats)
  gemm16<false, true><<<dim3(Tt / 64, Cc / 64, Bb), 256, 0, stream>>>(
      woh, Y, wyh, Wo_b, bsum, bsq,
      Cc, Tt, Ci, Ci, Tt, Tt, 0, (long)Ci * Tt, (long)Cc * Tt);

  // finalize
  final_kernel<<<(int)(SZ_WY / 4 / 256), 256, 0, stream>>>(
      wyh, x, gamma, beta, bsum, bsq, out);
}

// Round 2
// 343.919 us; speedup vs baseline: 2.3570x; 2.3570x over previous
//
#include <hip/hip_runtime.h>
#include <hip/hip_fp16.h>

typedef _Float16 f16;
typedef f16 f16x8 __attribute__((ext_vector_type(8)));
typedef f16 f16x4 __attribute__((ext_vector_type(4)));
typedef float f32x4 __attribute__((ext_vector_type(4)));

constexpr int Bb = 8, Cc = 1024, Tt = 2048, Ci = 512;
constexpr float BN_EPS = 1e-5f;

__device__ __forceinline__ void gload16(const f16* g, f16* l) {
  __builtin_amdgcn_global_load_lds(
      (const __attribute__((address_space(1))) void*)g,
      (__attribute__((address_space(3))) void*)l, 16, 0, 0);
}

// ---------------- fp32 -> fp16 convert (weights) ----------------
__global__ __launch_bounds__(256)
void cvt_kernel(const float* __restrict__ src, f16* __restrict__ dst, int n4) {
  int i = blockIdx.x * blockDim.x + threadIdx.x;
  if (i < n4) {
    float4 v = *((const float4*)src + i);
    f16x4 h;
    h[0] = (f16)v.x; h[1] = (f16)v.y; h[2] = (f16)v.z; h[3] = (f16)v.w;
    *((f16x4*)dst + i) = h;
  }
}

// ---------------- transpose-convert: x[b][c][t] f32 -> xT[b][t][c] f16 ----
__global__ __launch_bounds__(256)
void cvtT_kernel(const float* __restrict__ x, f16* __restrict__ xT) {
  __shared__ float tile[64][68];
  const int b = blockIdx.z, c0 = blockIdx.y * 64, t0 = blockIdx.x * 64;
  const int tid = threadIdx.x;
  const float* xp = x + ((long)b * Cc + c0) * Tt + t0;
  {
    int r = tid >> 4, c4 = (tid & 15) * 4;
    #pragma unroll
    for (int it = 0; it < 4; it++) {
      float4 v = *(const float4*)(xp + (long)(r + it * 16) * Tt + c4);
      *(float4*)&tile[r + it * 16][c4] = v;
    }
  }
  __syncthreads();
  f16* op = xT + ((long)b * Tt + t0) * Cc + c0;
  {
    int c8 = (tid & 7) * 8;
    #pragma unroll
    for (int it = 0; it < 2; it++) {
      int t = (tid >> 3) + it * 32;
      f16x8 o;
      #pragma unroll
      for (int jj = 0; jj < 8; jj++) o[jj] = (f16)tile[c8 + jj][t];
      *(f16x8*)(op + (long)t * Cc + c8) = o;
    }
  }
}

// ---------------- m97-style GEMM: C[m][n] = sum_k A[m][k]*B[n][k] ----------
// A: [M,K] k-innermost (lda), B: [N,K] k-innermost (ldb), C: [M,N] (ldc).
// BIAS_MODE: 0 none, 1 per-m, 2 per-n.
template<int BIAS_MODE>
__global__ __launch_bounds__(256)
void gemm128(const f16* __restrict__ A, const f16* __restrict__ B,
             f16* __restrict__ C, const float* __restrict__ bias,
             int K, int lda, int ldb, int ldc, long sA, long sB, long sC)
{
  __shared__ f16 la[128 * 32];
  __shared__ f16 lb[128 * 32];
  const int tid = threadIdx.x, lane = tid & 63, wv = tid >> 6;
  const int bm0 = blockIdx.y * 128, bn0 = blockIdx.x * 128;
  const int wm = (wv >> 1) * 64, wn = (wv & 1) * 64;
  A += (long)blockIdx.z * sA;
  B += (long)blockIdx.z * sB;
  C += (long)blockIdx.z * sC;
  const f16* Ab = A + (long)bm0 * lda;
  const f16* Bb_ = B + (long)bn0 * ldb;

  f32x4 acc[4][4] = {};
  const int r16 = lane & 15, kb = (lane >> 4) * 8;

  for (int k0 = 0; k0 < K; k0 += 32) {
    __syncthreads();
    #pragma unroll
    for (int it = 0; it < 2; it++) {
      int g = it * 256 + wv * 64 + lane;       // 16B chunk id in [0,512)
      int row = g >> 2, kq = (g & 3) << 3;
      gload16(Ab + (long)row * lda + k0 + kq, la + (long)(it * 256 + wv * 64) * 8);
      gload16(Bb_ + (long)row * ldb + k0 + kq, lb + (long)(it * 256 + wv * 64) * 8);
    }
    __syncthreads();
    f16x8 af[4], bf[4];
    #pragma unroll
    for (int i = 0; i < 4; i++) af[i] = *(const f16x8*)(la + (wm + i * 16 + r16) * 32 + kb);
    #pragma unroll
    for (int j = 0; j < 4; j++) bf[j] = *(const f16x8*)(lb + (wn + j * 16 + r16) * 32 + kb);
    #pragma unroll
    for (int i = 0; i < 4; i++)
      #pragma unroll
      for (int j = 0; j < 4; j++)
        acc[i][j] = __builtin_amdgcn_mfma_f32_16x16x32_f16(af[i], bf[j], acc[i][j], 0, 0, 0);
  }

  const int rg = (lane >> 4) * 4;
  #pragma unroll
  for (int i = 0; i < 4; i++) {
    int row = bm0 + wm + i * 16 + rg;
    #pragma unroll
    for (int j = 0; j < 4; j++) {
      int col = bn0 + wn + j * 16 + r16;
      float bn_ = (BIAS_MODE == 2) ? bias[col] : 0.0f;
      #pragma unroll
      for (int r = 0; r < 4; r++) {
        float v = acc[i][j][r] + ((BIAS_MODE == 1) ? bias[row + r] : bn_);
        C[(long)(row + r) * ldc + col] = (f16)v;
      }
    }
  }
}

// ---------------- per-row max & sum(exp) of St rows (softmax over q) -------
__global__ __launch_bounds__(256)
void rowstat_kernel(const f16* __restrict__ S, float* __restrict__ maxs,
                    float* __restrict__ sums) {
  __shared__ float red[8];
  const int tid = threadIdx.x;
  const f16* p = S + (long)blockIdx.x * Tt;
  f16x8 v = *((const f16x8*)p + tid);
  float f[8];
  float mx = -3e38f;
  #pragma unroll
  for (int j = 0; j < 8; j++) { f[j] = (float)v[j]; mx = fmaxf(mx, f[j]); }
  #pragma unroll
  for (int off = 1; off < 64; off <<= 1) mx = fmaxf(mx, __shfl_xor(mx, off));
  const int w = tid >> 6;
  if ((tid & 63) == 0) red[w] = mx;
  __syncthreads();
  mx = fmaxf(fmaxf(red[0], red[1]), fmaxf(red[2], red[3]));
  float sum = 0.f;
  #pragma unroll
  for (int j = 0; j < 8; j++) sum += __expf(f[j] - mx);
  #pragma unroll
  for (int off = 1; off < 64; off <<= 1) sum += __shfl_xor(sum, off);
  __syncthreads();
  if ((tid & 63) == 0) red[4 + w] = sum;
  __syncthreads();
  if (tid == 0) {
    maxs[blockIdx.x] = mx;
    sums[blockIdx.x] = (red[4] + red[5]) + (red[6] + red[7]);
  }
}

// ---------------- transpose + normalize: P[b][q][kt] = softmaxed St --------
__global__ __launch_bounds__(256)
void transnorm_kernel(const f16* __restrict__ St, const float* __restrict__ maxs,
                      const float* __restrict__ sums, f16* __restrict__ P) {
  __shared__ f16 tile[64][72];
  __shared__ float rm[64], ri[64];
  const int b = blockIdx.z, kt0 = blockIdx.y * 64, q0 = blockIdx.x * 64;
  const int tid = threadIdx.x;
  if (tid < 64) {
    rm[tid] = maxs[(long)b * Tt + kt0 + tid];
    ri[tid] = 1.0f / sums[(long)b * Tt + kt0 + tid];
  }
  const f16* Sp = St + ((long)b * Tt + kt0) * Tt + q0;
  {
    int r = tid >> 3, c8 = (tid & 7) * 8;
    #pragma unroll
    for (int it = 0; it < 2; it++) {
      f16x8 v = *(const f16x8*)(Sp + (long)(r + it * 32) * Tt + c8);
      *(f16x8*)&tile[r + it * 32][c8] = v;
    }
  }
  __syncthreads();
  f16* Pp = P + ((long)b * Tt + q0) * Tt + kt0;
  {
    int kt8 = (tid & 7) * 8;
    #pragma unroll
    for (int it = 0; it < 2; it++) {
      int q = (tid >> 3) + it * 32;
      f16x8 o;
      #pragma unroll
      for (int jj = 0; jj < 8; jj++) {
        int kt = kt8 + jj;
        o[jj] = (f16)(__expf((float)tile[kt][q] - rm[kt]) * ri[kt]);
      }
      *(f16x8*)(Pp + (long)q * Tt + kt8) = o;
    }
  }
}

// ---------------- BN stats per channel over (b,t) --------------------------
__global__ __launch_bounds__(256)
void bnstat_kernel(const f16* __restrict__ wy, float* __restrict__ bsum,
                   float* __restrict__ bsq) {
  const int c = blockIdx.x, tid = threadIdx.x;
  float s1 = 0.f, s2 = 0.f;
  for (int b = 0; b < Bb; b++) {
    f16x8 v = *((const f16x8*)(wy + ((long)b * Cc + c) * Tt) + tid);
    #pragma unroll
    for (int jj = 0; jj < 8; jj++) { float f = (float)v[jj]; s1 += f; s2 += f * f; }
  }
  #pragma unroll
  for (int off = 1; off < 64; off <<= 1) {
    s1 += __shfl_xor(s1, off);
    s2 += __shfl_xor(s2, off);
  }
  __shared__ float l1[4], l2[4];
  const int w = tid >> 6;
  if ((tid & 63) == 0) { l1[w] = s1; l2[w] = s2; }
  __syncthreads();
  if (tid == 0) {
    bsum[c] = (l1[0] + l1[1]) + (l1[2] + l1[3]);
    bsq[c]  = (l2[0] + l2[1]) + (l2[2] + l2[3]);
  }
}

// ---------------- finalize: BN + residual ----------------------------------
__global__ __launch_bounds__(256)
void final_kernel(const f16* __restrict__ wy, const float* __restrict__ x,
                  const float* __restrict__ gamma, const float* __restrict__ beta,
                  const float* __restrict__ bsum, const float* __restrict__ bsq,
                  float* __restrict__ out)
{
  long i = ((long)blockIdx.x * blockDim.x + threadIdx.x) * 4;
  int c = (int)((i >> 11) & (Cc - 1)); // T = 2048 = 2^11
  const float cnt = (float)Bb * (float)Tt;
  float mean = bsum[c] / cnt;
  float var  = bsq[c] / cnt - mean * mean;
  float sc = rsqrtf(var + BN_EPS) * gamma[c];
  float sh = beta[c] - mean * sc;
  f16x4 w = *(const f16x4*)(wy + i);
  float4 xv = *(const float4*)(x + i);
  float4 o;
  o.x = (float)w[0] * sc + sh + xv.x;
  o.y = (float)w[1] * sc + sh + xv.y;
  o.z = (float)w[2] * sc + sh + xv.z;
  o.w = (float)w[3] * sc + sh + xv.w;
  *(float4*)(out + i) = o;
}

// ---------------- host launch ----------------
extern "C" void kernel_launch(void* const* d_in, const int* in_sizes, int n_in,
                              void* d_out, int out_size, void* d_ws, size_t ws_size,
                              hipStream_t stream) {
  const float* x    = (const float*)d_in[0];
  const float* Wq_w = (const float*)d_in[1];
  const float* Wq_b = (const float*)d_in[2];
  const float* Wk_w = (const float*)d_in[3];
  const float* Wk_b = (const float*)d_in[4];
  const float* Wv_w = (const float*)d_in[5];
  const float* Wv_b = (const float*)d_in[6];
  const float* Wo_w = (const float*)d_in[7];
  const float* Wo_b = (const float*)d_in[8];
  const float* gamma = (const float*)d_in[9];
  const float* beta  = (const float*)d_in[10];
  float* out = (float*)d_out;

  constexpr long SZ_XT = (long)Bb * Tt * Cc;   // 16,777,216
  constexpr long SZ_Q  = (long)Bb * Tt * Ci;   // 8,388,608
  constexpr long SZ_S  = (long)Bb * Tt * Tt;   // 33,554,432
  constexpr long SZ_W  = (long)Ci * Cc;        // 524,288

  f16* ws = (f16*)d_ws;
  f16* xT = ws;                 // [B][T][C]   (dead after projections)
  f16* P  = ws;                 // [B][Tq][Tk] overlays xT+Q+K (exactly 33.6M halves)
  f16* Qm = ws + SZ_XT;         // [B][T][Ci]
  f16* Km = Qm + SZ_Q;          // [B][T][Ci]
  f16* Vt = Km + SZ_Q;          // [B][Ci][T]
  f16* St = Vt + SZ_Q;          // [B][Tk][Tq]
  f16* wq = St + SZ_S;
  f16* wk = wq + SZ_W;
  f16* wv = wk + SZ_W;
  f16* wo = wv + SZ_W;
  f16* Y  = wo + SZ_W;          // [B][Tq][Ci]
  f16* wy = Y + SZ_Q;           // [B][C][T]
  float* maxs = (float*)(wy + SZ_XT);
  float* sums = maxs + (long)Bb * Tt;
  float* bsum = sums + (long)Bb * Tt;
  float* bsq  = bsum + Cc;

  // weight converts
  cvt_kernel<<<(int)(SZ_W / 4 / 256), 256, 0, stream>>>(Wq_w, wq, (int)(SZ_W / 4));
  cvt_kernel<<<(int)(SZ_W / 4 / 256), 256, 0, stream>>>(Wk_w, wk, (int)(SZ_W / 4));
  cvt_kernel<<<(int)(SZ_W / 4 / 256), 256, 0, stream>>>(Wv_w, wv, (int)(SZ_W / 4));
  cvt_kernel<<<(int)(SZ_W / 4 / 256), 256, 0, stream>>>(Wo_w, wo, (int)(SZ_W / 4));
  // x transpose-convert
  cvtT_kernel<<<dim3(Tt / 64, Cc / 64, Bb), 256, 0, stream>>>(x, xT);

  // Q[t][o] = sum_c xT[t][c] Wq[o][c] + bq[o]   (bias per n)
  gemm128<2><<<dim3(Ci / 128, Tt / 128, Bb), 256, 0, stream>>>(
      xT, wq, Qm, Wq_b, Cc, Cc, Cc, Ci, (long)Tt * Cc, 0, (long)Tt * Ci);
  // K[t][o]
  gemm128<2><<<dim3(Ci / 128, Tt / 128, Bb), 256, 0, stream>>>(
      xT, wk, Km, Wk_b, Cc, Cc, Cc, Ci, (long)Tt * Cc, 0, (long)Tt * Ci);
  // Vt[o][t] = sum_c Wv[o][c] xT[t][c] + bv[o]  (bias per m)
  gemm128<1><<<dim3(Tt / 128, Ci / 128, Bb), 256, 0, stream>>>(
      wv, xT, Vt, Wv_b, Cc, Cc, Cc, Tt, 0, (long)Tt * Cc, (long)Ci * Tt);

  // St[kt][q] = sum_c K[kt][c] Q[q][c]
  gemm128<0><<<dim3(Tt / 128, Tt / 128, Bb), 256, 0, stream>>>(
      Km, Qm, St, nullptr, Ci, Ci, Ci, Tt, (long)Tt * Ci, (long)Tt * Ci, (long)Tt * Tt);

  // softmax over q: row stats then transpose+normalize into P[q][kt]
  rowstat_kernel<<<Bb * Tt, 256, 0, stream>>>(St, maxs, sums);
  transnorm_kernel<<<dim3(Tt / 64, Tt / 64, Bb), 256, 0, stream>>>(St, maxs, sums, P);

  // Y[q][c] = sum_kt P[q][kt] Vt[c][kt]
  gemm128<0><<<dim3(Ci / 128, Tt / 128, Bb), 256, 0, stream>>>(
      P, Vt, Y, nullptr, Tt, Tt, Tt, Ci, (long)Tt * Tt, (long)Ci * Tt, (long)Tt * Ci);

  // wy[o][t] = sum_c Wo[o][c] Y[t][c] + bo[o]  (bias per m)
  gemm128<1><<<dim3(Tt / 128, Cc / 128, Bb), 256, 0, stream>>>(
      wo, Y, wy, Wo_b, Ci, Ci, Ci, Tt, 0, (long)Tt * Ci, (long)Cc * Tt);

  // BN stats + finalize
  bnstat_kernel<<<Cc, 256, 0, stream>>>(wy, bsum, bsq);
  final_kernel<<<(int)(SZ_XT / 4 / 256), 256, 0, stream>>>(
      wy, x, gamma, beta, bsum, bsq, out);
}

// Round 3
// 299.248 us; speedup vs baseline: 2.7088x; 1.1493x over previous
//
#include <hip/hip_runtime.h>
#include <hip/hip_fp16.h>

typedef _Float16 f16;
typedef f16 f16x8 __attribute__((ext_vector_type(8)));
typedef f16 f16x4 __attribute__((ext_vector_type(4)));
typedef float f32x4 __attribute__((ext_vector_type(4)));

constexpr int Bb = 8, Cc = 1024, Tt = 2048, Ci = 512;
constexpr float BN_EPS = 1e-5f;

__device__ __forceinline__ void gload16(const f16* g, f16* l) {
  __builtin_amdgcn_global_load_lds(
      (const __attribute__((address_space(1))) void*)g,
      (__attribute__((address_space(3))) void*)l, 16, 0, 0);
}

// ---------------- fp32 -> fp16 convert (weights) ----------------
__global__ __launch_bounds__(256)
void cvt_kernel(const float* __restrict__ src, f16* __restrict__ dst, int n4) {
  int i = blockIdx.x * blockDim.x + threadIdx.x;
  if (i < n4) {
    float4 v = *((const float4*)src + i);
    f16x4 h;
    h[0] = (f16)v.x; h[1] = (f16)v.y; h[2] = (f16)v.z; h[3] = (f16)v.w;
    *((f16x4*)dst + i) = h;
  }
}

// ---------------- transpose-convert: x[b][c][t] f32 -> xT[b][t][c] f16 ----
__global__ __launch_bounds__(256)
void cvtT_kernel(const float* __restrict__ x, f16* __restrict__ xT) {
  __shared__ float tile[64][68];
  const int b = blockIdx.z, c0 = blockIdx.y * 64, t0 = blockIdx.x * 64;
  const int tid = threadIdx.x;
  const float* xp = x + ((long)b * Cc + c0) * Tt + t0;
  {
    int r = tid >> 4, c4 = (tid & 15) * 4;
    #pragma unroll
    for (int it = 0; it < 4; it++) {
      float4 v = *(const float4*)(xp + (long)(r + it * 16) * Tt + c4);
      *(float4*)&tile[r + it * 16][c4] = v;
    }
  }
  __syncthreads();
  f16* op = xT + ((long)b * Tt + t0) * Cc + c0;
  {
    int c8 = (tid & 7) * 8;
    #pragma unroll
    for (int it = 0; it < 2; it++) {
      int t = (tid >> 3) + it * 32;
      f16x8 o;
      #pragma unroll
      for (int jj = 0; jj < 8; jj++) o[jj] = (f16)tile[c8 + jj][t];
      *(f16x8*)(op + (long)t * Cc + c8) = o;
    }
  }
}

// ---------------- 8-wave phased GEMM: C[m][n] = sum_k A[m][k]*B[n][k] ------
// BM=256, BN=128, BK=64. A:[M,K] (lda), B:[N,K] (ldb), C:[M,N] (ldc).
// Triple-buffered LDS ring; counted vmcnt(6); XOR bank swizzle; setprio MFMA.
// BIAS_MODE: 0 none, 1 per-m, 2 per-n.
template<int BIAS_MODE>
__global__ __launch_bounds__(512, 2)
void gemm8p(const f16* __restrict__ A, const f16* __restrict__ B,
            f16* __restrict__ C, const float* __restrict__ bias,
            int K, int lda, int ldb, int ldc, long sA, long sB, long sC)
{
  extern __shared__ f16 lds[];
  constexpr int TILE_A = 256 * 64;           // halves (32 KiB)
  constexpr int TILE_B = 128 * 64;           // halves (16 KiB)
  constexpr int TILE   = TILE_A + TILE_B;    // 24576 halves (48 KiB)

  const int tid = threadIdx.x, lane = tid & 63, wv = tid >> 6;
  const int bm0 = blockIdx.y * 256, bn0 = blockIdx.x * 128;
  const int wm = (wv >> 1) * 64, wn = (wv & 1) * 64;
  const f16* Ab = A + (long)blockIdx.z * sA + (long)bm0 * lda;
  const f16* Bt = B + (long)blockIdx.z * sB + (long)bn0 * ldb;
  C += (long)blockIdx.z * sC;

  const int r16 = lane & 15, khi = lane >> 4;
  const int sw = (r16 & 7) << 4;             // read-side XOR swizzle

  // staging: linear LDS dest (wave-uniform base + lane*16), pre-swizzled src
  auto stA = [&](int slot, int k0, int r) {
    int L = (r * 512 + tid) * 16;
    int G = L ^ (((L >> 7) & 7) << 4);
    gload16(Ab + (long)(G >> 7) * lda + k0 + ((G & 127) >> 1),
            lds + (long)slot * TILE + (r * 512 + wv * 64) * 8);
  };
  auto stB = [&](int slot, int k0, int r) {
    int L = (r * 512 + tid) * 16;
    int G = L ^ (((L >> 7) & 7) << 4);
    gload16(Bt + (long)(G >> 7) * ldb + k0 + ((G & 127) >> 1),
            lds + (long)slot * TILE + TILE_A + (r * 512 + wv * 64) * 8);
  };

  f32x4 acc[4][4] = {};
  const int nt = K >> 6;

  // prologue: stage tiles 0 and 1 (6 loads each)
  #pragma unroll
  for (int r = 0; r < 4; r++) stA(0, 0, r);
  #pragma unroll
  for (int r = 0; r < 2; r++) stB(0, 0, r);
  #pragma unroll
  for (int r = 0; r < 4; r++) stA(1, 64, r);
  #pragma unroll
  for (int r = 0; r < 2; r++) stB(1, 64, r);
  asm volatile("s_waitcnt vmcnt(6)" ::: "memory");   // tile0 landed, tile1 in flight
  __builtin_amdgcn_s_barrier();

  for (int t = 0; t < nt; t++) {
    const int slot = t % 3;
    const int nslot = (t + 2) % 3;
    const int k2 = (t + 2) << 6;
    const bool st = (t + 2) < nt;
    const char* baseA = (const char*)(lds + (long)slot * TILE);
    const char* baseB = (const char*)(lds + (long)slot * TILE + TILE_A);

    f16x8 af[4], bf[4];
    // ---- phase 0: k-slice 0 ----
    if (st) { stA(nslot, k2, 0); stA(nslot, k2, 1); stA(nslot, k2, 2); }
    #pragma unroll
    for (int mi = 0; mi < 4; mi++)
      af[mi] = *(const f16x8*)(baseA + (((wm + mi * 16 + r16) * 128 + khi * 16) ^ sw));
    #pragma unroll
    for (int nj = 0; nj < 4; nj++)
      bf[nj] = *(const f16x8*)(baseB + (((wn + nj * 16 + r16) * 128 + khi * 16) ^ sw));
    __builtin_amdgcn_s_setprio(1);
    #pragma unroll
    for (int mi = 0; mi < 4; mi++)
      #pragma unroll
      for (int nj = 0; nj < 4; nj++)
        acc[mi][nj] = __builtin_amdgcn_mfma_f32_16x16x32_f16(af[mi], bf[nj], acc[mi][nj], 0, 0, 0);
    __builtin_amdgcn_s_setprio(0);
    __builtin_amdgcn_s_barrier();

    // ---- phase 1: k-slice 1 ----
    if (st) { stA(nslot, k2, 3); stB(nslot, k2, 0); stB(nslot, k2, 1); }
    #pragma unroll
    for (int mi = 0; mi < 4; mi++)
      af[mi] = *(const f16x8*)(baseA + (((wm + mi * 16 + r16) * 128 + 64 + khi * 16) ^ sw));
    #pragma unroll
    for (int nj = 0; nj < 4; nj++)
      bf[nj] = *(const f16x8*)(baseB + (((wn + nj * 16 + r16) * 128 + 64 + khi * 16) ^ sw));
    __builtin_amdgcn_s_setprio(1);
    #pragma unroll
    for (int mi = 0; mi < 4; mi++)
      #pragma unroll
      for (int nj = 0; nj < 4; nj++)
        acc[mi][nj] = __builtin_amdgcn_mfma_f32_16x16x32_f16(af[mi], bf[nj], acc[mi][nj], 0, 0, 0);
    __builtin_amdgcn_s_setprio(0);

    // ---- tile boundary: counted vmcnt (never 0 in steady state) ----
    __builtin_amdgcn_sched_barrier(0);
    if (st) asm volatile("s_waitcnt vmcnt(6)" ::: "memory");
    else    asm volatile("s_waitcnt vmcnt(0)" ::: "memory");
    __builtin_amdgcn_s_barrier();
  }

  // epilogue
  const int rg = khi * 4;
  #pragma unroll
  for (int mi = 0; mi < 4; mi++) {
    const int row = bm0 + wm + mi * 16 + rg;
    #pragma unroll
    for (int nj = 0; nj < 4; nj++) {
      const int col = bn0 + wn + nj * 16 + r16;
      const float bn_ = (BIAS_MODE == 2) ? bias[col] : 0.0f;
      #pragma unroll
      for (int r = 0; r < 4; r++) {
        float v = acc[mi][nj][r] + ((BIAS_MODE == 1) ? bias[row + r] : bn_);
        C[(long)(row + r) * ldc + col] = (f16)v;
      }
    }
  }
}

// ---------------- per-row max & sum(exp) of St rows (softmax over q) -------
__global__ __launch_bounds__(256)
void rowstat_kernel(const f16* __restrict__ S, float* __restrict__ maxs,
                    float* __restrict__ sums) {
  __shared__ float red[8];
  const int tid = threadIdx.x;
  const f16* p = S + (long)blockIdx.x * Tt;
  f16x8 v = *((const f16x8*)p + tid);
  float f[8];
  float mx = -3e38f;
  #pragma unroll
  for (int j = 0; j < 8; j++) { f[j] = (float)v[j]; mx = fmaxf(mx, f[j]); }
  #pragma unroll
  for (int off = 1; off < 64; off <<= 1) mx = fmaxf(mx, __shfl_xor(mx, off));
  const int w = tid >> 6;
  if ((tid & 63) == 0) red[w] = mx;
  __syncthreads();
  mx = fmaxf(fmaxf(red[0], red[1]), fmaxf(red[2], red[3]));
  float sum = 0.f;
  #pragma unroll
  for (int j = 0; j < 8; j++) sum += __expf(f[j] - mx);
  #pragma unroll
  for (int off = 1; off < 64; off <<= 1) sum += __shfl_xor(sum, off);
  __syncthreads();
  if ((tid & 63) == 0) red[4 + w] = sum;
  __syncthreads();
  if (tid == 0) {
    maxs[blockIdx.x] = mx;
    sums[blockIdx.x] = (red[4] + red[5]) + (red[6] + red[7]);
  }
}

// ---------------- transpose + normalize: P[b][q][kt] = softmaxed St --------
__global__ __launch_bounds__(256)
void transnorm_kernel(const f16* __restrict__ St, const float* __restrict__ maxs,
                      const float* __restrict__ sums, f16* __restrict__ P) {
  __shared__ f16 tile[64][72];
  __shared__ float rm[64], ri[64];
  const int b = blockIdx.z, kt0 = blockIdx.y * 64, q0 = blockIdx.x * 64;
  const int tid = threadIdx.x;
  if (tid < 64) {
    rm[tid] = maxs[(long)b * Tt + kt0 + tid];
    ri[tid] = 1.0f / sums[(long)b * Tt + kt0 + tid];
  }
  const f16* Sp = St + ((long)b * Tt + kt0) * Tt + q0;
  {
    int r = tid >> 3, c8 = (tid & 7) * 8;
    #pragma unroll
    for (int it = 0; it < 2; it++) {
      f16x8 v = *(const f16x8*)(Sp + (long)(r + it * 32) * Tt + c8);
      *(f16x8*)&tile[r + it * 32][c8] = v;
    }
  }
  __syncthreads();
  f16* Pp = P + ((long)b * Tt + q0) * Tt + kt0;
  {
    int kt8 = (tid & 7) * 8;
    #pragma unroll
    for (int it = 0; it < 2; it++) {
      int q = (tid >> 3) + it * 32;
      f16x8 o;
      #pragma unroll
      for (int jj = 0; jj < 8; jj++) {
        int kt = kt8 + jj;
        o[jj] = (f16)(__expf((float)tile[kt][q] - rm[kt]) * ri[kt]);
      }
      *(f16x8*)(Pp + (long)q * Tt + kt8) = o;
    }
  }
}

// ---------------- BN stats per channel over (b,t) --------------------------
__global__ __launch_bounds__(256)
void bnstat_kernel(const f16* __restrict__ wy, float* __restrict__ bsum,
                   float* __restrict__ bsq) {
  const int c = blockIdx.x, tid = threadIdx.x;
  float s1 = 0.f, s2 = 0.f;
  for (int b = 0; b < Bb; b++) {
    f16x8 v = *((const f16x8*)(wy + ((long)b * Cc + c) * Tt) + tid);
    #pragma unroll
    for (int jj = 0; jj < 8; jj++) { float f = (float)v[jj]; s1 += f; s2 += f * f; }
  }
  #pragma unroll
  for (int off = 1; off < 64; off <<= 1) {
    s1 += __shfl_xor(s1, off);
    s2 += __shfl_xor(s2, off);
  }
  __shared__ float l1[4], l2[4];
  const int w = tid >> 6;
  if ((tid & 63) == 0) { l1[w] = s1; l2[w] = s2; }
  __syncthreads();
  if (tid == 0) {
    bsum[c] = (l1[0] + l1[1]) + (l1[2] + l1[3]);
    bsq[c]  = (l2[0] + l2[1]) + (l2[2] + l2[3]);
  }
}

// ---------------- finalize: BN + residual ----------------------------------
__global__ __launch_bounds__(256)
void final_kernel(const f16* __restrict__ wy, const float* __restrict__ x,
                  const float* __restrict__ gamma, const float* __restrict__ beta,
                  const float* __restrict__ bsum, const float* __restrict__ bsq,
                  float* __restrict__ out)
{
  long i = ((long)blockIdx.x * blockDim.x + threadIdx.x) * 4;
  int c = (int)((i >> 11) & (Cc - 1)); // T = 2048 = 2^11
  const float cnt = (float)Bb * (float)Tt;
  float mean = bsum[c] / cnt;
  float var  = bsq[c] / cnt - mean * mean;
  float sc = rsqrtf(var + BN_EPS) * gamma[c];
  float sh = beta[c] - mean * sc;
  f16x4 w = *(const f16x4*)(wy + i);
  float4 xv = *(const float4*)(x + i);
  float4 o;
  o.x = (float)w[0] * sc + sh + xv.x;
  o.y = (float)w[1] * sc + sh + xv.y;
  o.z = (float)w[2] * sc + sh + xv.z;
  o.w = (float)w[3] * sc + sh + xv.w;
  *(float4*)(out + i) = o;
}

// ---------------- host launch ----------------
extern "C" void kernel_launch(void* const* d_in, const int* in_sizes, int n_in,
                              void* d_out, int out_size, void* d_ws, size_t ws_size,
                              hipStream_t stream) {
  const float* x    = (const float*)d_in[0];
  const float* Wq_w = (const float*)d_in[1];
  const float* Wq_b = (const float*)d_in[2];
  const float* Wk_w = (const float*)d_in[3];
  const float* Wk_b = (const float*)d_in[4];
  const float* Wv_w = (const float*)d_in[5];
  const float* Wv_b = (const float*)d_in[6];
  const float* Wo_w = (const float*)d_in[7];
  const float* Wo_b = (const float*)d_in[8];
  const float* gamma = (const float*)d_in[9];
  const float* beta  = (const float*)d_in[10];
  float* out = (float*)d_out;

  constexpr long SZ_XT = (long)Bb * Tt * Cc;   // 16,777,216
  constexpr long SZ_Q  = (long)Bb * Tt * Ci;   // 8,388,608
  constexpr long SZ_S  = (long)Bb * Tt * Tt;   // 33,554,432
  constexpr long SZ_W  = (long)Ci * Cc;        // 524,288

  f16* ws = (f16*)d_ws;
  f16* xT = ws;                 // [B][T][C]   (dead after projections)
  f16* P  = ws;                 // [B][Tq][Tk] overlays xT+Q+K
  f16* Qm = ws + SZ_XT;         // [B][T][Ci]
  f16* Km = Qm + SZ_Q;          // [B][T][Ci]
  f16* Vt = Km + SZ_Q;          // [B][Ci][T]
  f16* St = Vt + SZ_Q;          // [B][Tk][Tq]
  f16* wq = St + SZ_S;
  f16* wk = wq + SZ_W;
  f16* wv = wk + SZ_W;
  f16* wo = wv + SZ_W;
  f16* Y  = wo + SZ_W;          // [B][Tq][Ci]
  f16* wy = Y + SZ_Q;           // [B][C][T]
  float* maxs = (float*)(wy + SZ_XT);
  float* sums = maxs + (long)Bb * Tt;
  float* bsum = sums + (long)Bb * Tt;
  float* bsq  = bsum + Cc;

  constexpr int LDSB = (256 * 64 + 128 * 64) * 3 * 2; // 147456 B
  hipFuncSetAttribute(reinterpret_cast<const void*>(gemm8p<0>),
                      hipFuncAttributeMaxDynamicSharedMemorySize, LDSB);
  hipFuncSetAttribute(reinterpret_cast<const void*>(gemm8p<1>),
                      hipFuncAttributeMaxDynamicSharedMemorySize, LDSB);
  hipFuncSetAttribute(reinterpret_cast<const void*>(gemm8p<2>),
                      hipFuncAttributeMaxDynamicSharedMemorySize, LDSB);

  // weight converts
  cvt_kernel<<<(int)(SZ_W / 4 / 256), 256, 0, stream>>>(Wq_w, wq, (int)(SZ_W / 4));
  cvt_kernel<<<(int)(SZ_W / 4 / 256), 256, 0, stream>>>(Wk_w, wk, (int)(SZ_W / 4));
  cvt_kernel<<<(int)(SZ_W / 4 / 256), 256, 0, stream>>>(Wv_w, wv, (int)(SZ_W / 4));
  cvt_kernel<<<(int)(SZ_W / 4 / 256), 256, 0, stream>>>(Wo_w, wo, (int)(SZ_W / 4));
  // x transpose-convert
  cvtT_kernel<<<dim3(Tt / 64, Cc / 64, Bb), 256, 0, stream>>>(x, xT);

  // Q[t][o] = sum_c xT[t][c] Wq[o][c] + bq[o]   (bias per n)
  gemm8p<2><<<dim3(Ci / 128, Tt / 256, Bb), 512, LDSB, stream>>>(
      xT, wq, Qm, Wq_b, Cc, Cc, Cc, Ci, (long)Tt * Cc, 0, (long)Tt * Ci);
  // K[t][o]
  gemm8p<2><<<dim3(Ci / 128, Tt / 256, Bb), 512, LDSB, stream>>>(
      xT, wk, Km, Wk_b, Cc, Cc, Cc, Ci, (long)Tt * Cc, 0, (long)Tt * Ci);
  // Vt[o][t] = sum_c Wv[o][c] xT[t][c] + bv[o]  (bias per m)
  gemm8p<1><<<dim3(Tt / 128, Ci / 256, Bb), 512, LDSB, stream>>>(
      wv, xT, Vt, Wv_b, Cc, Cc, Cc, Tt, 0, (long)Tt * Cc, (long)Ci * Tt);

  // St[kt][q] = sum_c K[kt][c] Q[q][c]
  gemm8p<0><<<dim3(Tt / 128, Tt / 256, Bb), 512, LDSB, stream>>>(
      Km, Qm, St, nullptr, Ci, Ci, Ci, Tt, (long)Tt * Ci, (long)Tt * Ci, (long)Tt * Tt);

  // softmax over q: row stats then transpose+normalize into P[q][kt]
  rowstat_kernel<<<Bb * Tt, 256, 0, stream>>>(St, maxs, sums);
  transnorm_kernel<<<dim3(Tt / 64, Tt / 64, Bb), 256, 0, stream>>>(St, maxs, sums, P);

  // Y[q][c] = sum_kt P[q][kt] Vt[c][kt]
  gemm8p<0><<<dim3(Ci / 128, Tt / 256, Bb), 512, LDSB, stream>>>(
      P, Vt, Y, nullptr, Tt, Tt, Tt, Ci, (long)Tt * Tt, (long)Ci * Tt, (long)Tt * Ci);

  // wy[o][t] = sum_c Wo[o][c] Y[t][c] + bo[o]  (bias per m)
  gemm8p<1><<<dim3(Tt / 128, Cc / 256, Bb), 512, LDSB, stream>>>(
      wo, Y, wy, Wo_b, Ci, Ci, Ci, Tt, 0, (long)Tt * Ci, (long)Cc * Tt);

  // BN stats + finalize
  bnstat_kernel<<<Cc, 256, 0, stream>>>(wy, bsum, bsq);
  final_kernel<<<(int)(SZ_XT / 4 / 256), 256, 0, stream>>>(
      wy, x, gamma, beta, bsum, bsq, out);
}